// Round 4
// baseline (406.510 us; speedup 1.0000x reference)
//
#include <hip/hip_runtime.h>
#include <hip/hip_bf16.h>
#include <hip/hip_fp16.h>

#define IN_F 4096
#define OUT_F 16384
#define TOKENS 64
#define BLOCK 256                 // 4 waves; each wave = 16 channels x K/4
#define KQUART (IN_F / 4)         // 1024
#define NITER (KQUART / 32)       // 32 K-steps per wave

typedef __attribute__((ext_vector_type(8))) short bf16x8;
typedef __attribute__((ext_vector_type(8))) unsigned short u16x8;
typedef __attribute__((ext_vector_type(4))) float f32x4;
typedef __attribute__((ext_vector_type(4))) int i32x4;

enum { F_BF16 = 0, F_FP16 = 1, F_FP32 = 2 };

__device__ __forceinline__ float dec_bf16(unsigned short h) {
    return __uint_as_float(((unsigned)h) << 16);
}
__device__ __forceinline__ float dec_fp16(unsigned short h) {
    __half_raw hr; hr.x = h;
    return __half2float(__half(hr));
}
__device__ __forceinline__ unsigned short enc_bf16_rne(float f) {
    unsigned u = __float_as_uint(f);
    u += 0x7FFFu + ((u >> 16) & 1u);
    return (unsigned short)(u >> 16);
}

// Wave-uniform format detection (verified passing rounds 2-3 — keep verbatim).
__device__ __forceinline__ int detect_fmt16(const void* p, int lane, float lo, float hi) {
    unsigned short h = ((const unsigned short*)p)[lane];
    float vb = fabsf(dec_bf16(h));
    float vh = fabsf(dec_fp16(h));
    int cb = __popcll(__ballot(vb > lo && vb < hi));
    int ch = __popcll(__ballot(vh > lo && vh < hi));
    return (cb >= 56) ? F_BF16 : (ch >= 56) ? F_FP16 : F_FP32;
}
__device__ __forceinline__ int detect_wint(const int* w, int lane) {
    int v = w[lane];
    int ci = __popcll(__ballot(v >= -127 && v <= 127));
    return (ci >= 56) ? 1 : 0;
}

// ---------------- pre-kernel: x -> bf16 into workspace (verified round 3) ----
__global__ __launch_bounds__(256) void prep_x(const void* __restrict__ xv,
                                              unsigned short* __restrict__ xbf) {
    const int tid  = blockIdx.x * 256 + threadIdx.x;  // 16384 threads, 16 elem each
    const int lane = threadIdx.x & 63;
    const int xf = detect_fmt16(xv, lane, 9.7e-4f, 64.0f);

    if (xf == F_BF16) {
        u16x8 a = ((const u16x8*)xv)[tid * 2];
        u16x8 b = ((const u16x8*)xv)[tid * 2 + 1];
        ((u16x8*)xbf)[tid * 2]     = a;
        ((u16x8*)xbf)[tid * 2 + 1] = b;
    } else if (xf == F_FP32) {
        u16x8 o[2];
        #pragma unroll
        for (int half = 0; half < 2; ++half) {
            f32x4 v0 = ((const f32x4*)xv)[tid * 4 + half * 2];
            f32x4 v1 = ((const f32x4*)xv)[tid * 4 + half * 2 + 1];
            #pragma unroll
            for (int j = 0; j < 4; ++j) {
                o[half][j]     = enc_bf16_rne(v0[j]);
                o[half][j + 4] = enc_bf16_rne(v1[j]);
            }
        }
        ((u16x8*)xbf)[tid * 2]     = o[0];
        ((u16x8*)xbf)[tid * 2 + 1] = o[1];
    } else { // F_FP16
        #pragma unroll
        for (int half = 0; half < 2; ++half) {
            u16x8 v = ((const u16x8*)xv)[tid * 2 + half];
            u16x8 o;
            #pragma unroll
            for (int j = 0; j < 8; ++j) o[j] = enc_bf16_rne(dec_fp16(v[j]));
            ((u16x8*)xbf)[tid * 2 + half] = o;
        }
    }
}

// ---------------- main: direct-stream, register double-buffered K-loop -------
template <int WINT>
__device__ __forceinline__ void kloop(const int* __restrict__ wp,     // w + n*IN_F (lane's channel)
                                      const short* __restrict__ xs,   // xbf
                                      int kbase, int ln, int kq,
                                      f32x4 acc[4]) {
    const short* x0 = xs + (size_t)(ln     ) * IN_F;
    const short* x1 = xs + (size_t)(ln + 16) * IN_F;
    const short* x2 = xs + (size_t)(ln + 32) * IN_F;
    const short* x3 = xs + (size_t)(ln + 48) * IN_F;

    int k = kbase + kq * 8;

    // prologue: load iteration 0
    i32x4  cb0 = *(const i32x4*)(wp + k);
    i32x4  cb1 = *(const i32x4*)(wp + k + 4);
    bf16x8 ca0 = *(const bf16x8*)(x0 + k);
    bf16x8 ca1 = *(const bf16x8*)(x1 + k);
    bf16x8 ca2 = *(const bf16x8*)(x2 + k);
    bf16x8 ca3 = *(const bf16x8*)(x3 + k);

    for (int t = 0; t < NITER; ++t) {
        // issue next iteration's loads FIRST (B from HBM, A from L2-hot xbf)
        const int kn = (t + 1 < NITER) ? (k + 32) : (kbase + kq * 8);
        i32x4  nb0 = *(const i32x4*)(wp + kn);
        i32x4  nb1 = *(const i32x4*)(wp + kn + 4);
        bf16x8 na0 = *(const bf16x8*)(x0 + kn);
        bf16x8 na1 = *(const bf16x8*)(x1 + kn);
        bf16x8 na2 = *(const bf16x8*)(x2 + kn);
        bf16x8 na3 = *(const bf16x8*)(x3 + kn);

        // compute current iteration from registers
        bf16x8 bfrag;
        #pragma unroll
        for (int j = 0; j < 4; ++j) {
            unsigned f0 = WINT ? __float_as_uint((float)cb0[j]) : (unsigned)cb0[j];
            unsigned f1 = WINT ? __float_as_uint((float)cb1[j]) : (unsigned)cb1[j];
            bfrag[j]     = (short)(f0 >> 16);   // int8-valued -> bf16 exact
            bfrag[j + 4] = (short)(f1 >> 16);
        }
        acc[0] = __builtin_amdgcn_mfma_f32_16x16x32_bf16(ca0, bfrag, acc[0], 0, 0, 0);
        acc[1] = __builtin_amdgcn_mfma_f32_16x16x32_bf16(ca1, bfrag, acc[1], 0, 0, 0);
        acc[2] = __builtin_amdgcn_mfma_f32_16x16x32_bf16(ca2, bfrag, acc[2], 0, 0, 0);
        acc[3] = __builtin_amdgcn_mfma_f32_16x16x32_bf16(ca3, bfrag, acc[3], 0, 0, 0);

        // rotate (the single combined waitcnt lands here, after compute)
        cb0 = nb0; cb1 = nb1;
        ca0 = na0; ca1 = na1; ca2 = na2; ca3 = na3;
        k = kn;
    }
}

__global__ __launch_bounds__(BLOCK, 4) void w8a16_main(
    const void* __restrict__ xv_orig, const int* __restrict__ w,
    const void* __restrict__ sv, const void* __restrict__ bv,
    void* __restrict__ yv, const unsigned short* __restrict__ xbf) {

    __shared__ float red[4][64][17];   // cross-wave K-reduce, +1 pad

    const int tid  = threadIdx.x;
    const int wv   = tid >> 6;         // 0..3: K-quarter
    const int lane = tid & 63;
    const int ln   = lane & 15;
    const int kq   = lane >> 4;

    const int xf = detect_fmt16(xv_orig, lane, 9.7e-4f, 64.0f);
    const int sf = detect_fmt16(sv, lane, 1.0e-4f, 0.25f);
    const int wi = detect_wint(w, lane);

    const int    n     = blockIdx.x * 16 + ln;
    const int*   wp    = w + (size_t)n * IN_F;
    const int    kbase = wv * KQUART;

    f32x4 acc[4] = {};
    if (wi) kloop<1>(wp, (const short*)xbf, kbase, ln, kq, acc);
    else    kloop<0>(wp, (const short*)xbf, kbase, ln, kq, acc);

    #pragma unroll
    for (int i = 0; i < 4; ++i)
        #pragma unroll
        for (int r2 = 0; r2 < 4; ++r2)
            red[wv][lane][i * 4 + r2] = acc[i][r2];
    __syncthreads();

    if (wv == 0) {
        #pragma unroll
        for (int i = 0; i < 4; ++i)
            #pragma unroll
            for (int r2 = 0; r2 < 4; ++r2)
                acc[i][r2] += red[1][lane][i * 4 + r2]
                            + red[2][lane][i * 4 + r2]
                            + red[3][lane][i * 4 + r2];

        float scale, bias;
        if (sf == F_FP32) {
            scale = ((const float*)sv)[n];
            bias  = ((const float*)bv)[n];
        } else if (sf == F_BF16) {
            scale = dec_bf16(((const unsigned short*)sv)[n]);
            bias  = dec_bf16(((const unsigned short*)bv)[n]);
        } else {
            scale = dec_fp16(((const unsigned short*)sv)[n]);
            bias  = dec_fp16(((const unsigned short*)bv)[n]);
        }

        // D layout (m89-verified): col = ln (= n), row m = 16*tile + kq*4 + reg
        #pragma unroll
        for (int i = 0; i < 4; ++i) {
            #pragma unroll
            for (int r2 = 0; r2 < 4; ++r2) {
                const int    m   = 16 * i + kq * 4 + r2;
                const float  val = acc[i][r2] * scale + bias;
                const size_t o   = (size_t)m * OUT_F + n;
                if (xf == F_FP32)      ((float*)yv)[o] = val;
                else if (xf == F_BF16) ((unsigned short*)yv)[o] = enc_bf16_rne(val);
                else                   ((__half*)yv)[o] = __float2half(val);
            }
        }
    }
}

extern "C" void kernel_launch(void* const* d_in, const int* in_sizes, int n_in,
                              void* d_out, int out_size, void* d_ws, size_t ws_size,
                              hipStream_t stream) {
    unsigned short* xbf = (unsigned short*)d_ws;   // 512 KB: x as bf16
    prep_x<<<64, 256, 0, stream>>>(d_in[0], xbf);
    w8a16_main<<<OUT_F / 16, BLOCK, 0, stream>>>(d_in[0], (const int*)d_in[1],
                                                 d_in[2], d_in[3], d_out, xbf);
}

// Round 5
// 388.473 us; speedup vs baseline: 1.0464x; 1.0464x over previous
//
#include <hip/hip_runtime.h>
#include <hip/hip_bf16.h>
#include <hip/hip_fp16.h>

#define IN_F 4096
#define OUT_F 16384
#define TOKENS 64

#define NCH 64                  // channels per block
#define KT 64                   // k per tile
#define KHALF 2048              // K per block (K-split 2)
#define NTILES (KHALF / KT)     // 32
#define BLOCK 256

typedef __attribute__((ext_vector_type(8))) short bf16x8;
typedef __attribute__((ext_vector_type(8))) unsigned short u16x8;
typedef __attribute__((ext_vector_type(4))) unsigned short u16x4;
typedef __attribute__((ext_vector_type(4))) float f32x4;
typedef __attribute__((ext_vector_type(4))) int i32x4;

enum { F_BF16 = 0, F_FP16 = 1, F_FP32 = 2 };

__device__ __forceinline__ float dec_bf16(unsigned short h) {
    return __uint_as_float(((unsigned)h) << 16);
}
__device__ __forceinline__ float dec_fp16(unsigned short h) {
    __half_raw hr; hr.x = h;
    return __half2float(__half(hr));
}
__device__ __forceinline__ unsigned short enc_bf16_rne(float f) {
    unsigned u = __float_as_uint(f);
    u += 0x7FFFu + ((u >> 16) & 1u);
    return (unsigned short)(u >> 16);
}

// Wave-uniform format detection (verified passing rounds 2-4 — keep verbatim).
__device__ __forceinline__ int detect_fmt16(const void* p, int lane, float lo, float hi) {
    unsigned short h = ((const unsigned short*)p)[lane];
    float vb = fabsf(dec_bf16(h));
    float vh = fabsf(dec_fp16(h));
    int cb = __popcll(__ballot(vb > lo && vb < hi));
    int ch = __popcll(__ballot(vh > lo && vh < hi));
    return (cb >= 56) ? F_BF16 : (ch >= 56) ? F_FP16 : F_FP32;
}
__device__ __forceinline__ int detect_wint(const int* w, int lane) {
    int v = w[lane];
    int ci = __popcll(__ballot(v >= -127 && v <= 127));
    return (ci >= 56) ? 1 : 0;
}

// ---------------- pre-kernel: x -> bf16 into workspace (verified) ------------
__global__ __launch_bounds__(256) void prep_x(const void* __restrict__ xv,
                                              unsigned short* __restrict__ xbf) {
    const int tid  = blockIdx.x * 256 + threadIdx.x;
    const int lane = threadIdx.x & 63;
    const int xf = detect_fmt16(xv, lane, 9.7e-4f, 64.0f);

    if (xf == F_BF16) {
        u16x8 a = ((const u16x8*)xv)[tid * 2];
        u16x8 b = ((const u16x8*)xv)[tid * 2 + 1];
        ((u16x8*)xbf)[tid * 2]     = a;
        ((u16x8*)xbf)[tid * 2 + 1] = b;
    } else if (xf == F_FP32) {
        u16x8 o[2];
        #pragma unroll
        for (int half = 0; half < 2; ++half) {
            f32x4 v0 = ((const f32x4*)xv)[tid * 4 + half * 2];
            f32x4 v1 = ((const f32x4*)xv)[tid * 4 + half * 2 + 1];
            #pragma unroll
            for (int j = 0; j < 4; ++j) {
                o[half][j]     = enc_bf16_rne(v0[j]);
                o[half][j + 4] = enc_bf16_rne(v1[j]);
            }
        }
        ((u16x8*)xbf)[tid * 2]     = o[0];
        ((u16x8*)xbf)[tid * 2 + 1] = o[1];
    } else { // F_FP16
        #pragma unroll
        for (int half = 0; half < 2; ++half) {
            u16x8 v = ((const u16x8*)xv)[tid * 2 + half];
            u16x8 o;
            #pragma unroll
            for (int j = 0; j < 8; ++j) o[j] = enc_bf16_rne(dec_fp16(v[j]));
            ((u16x8*)xbf)[tid * 2 + half] = o;
        }
    }
}

// ---------------- main: m97-style dual staged tiles, f32 partials ------------
template <int WINT>
__device__ __forceinline__ void tile_compute(const char* __restrict__ bB,
                                             const char* __restrict__ bA,
                                             int wv, int ln, int kq, f32x4 acc[4]) {
    const char* brow = bB + (wv * 16 + ln) * 256;   // B row stride = KT*4 = 256 B
    #pragma unroll
    for (int s = 0; s < 2; ++s) {                   // 2 K-steps of 32 per tile
        const int c0 = s * 8 + kq * 2;              // B 16B-chunk, XOR-ln swizzled
        i32x4 b0 = *(const i32x4*)(brow + ((c0)     ^ ln) * 16);
        i32x4 b1 = *(const i32x4*)(brow + ((c0 + 1) ^ ln) * 16);
        bf16x8 bfrag;
        #pragma unroll
        for (int j = 0; j < 4; ++j) {
            unsigned f0 = WINT ? __float_as_uint((float)b0[j]) : (unsigned)b0[j];
            unsigned f1 = WINT ? __float_as_uint((float)b1[j]) : (unsigned)b1[j];
            bfrag[j]     = (short)(f0 >> 16);       // int8-valued -> bf16 exact
            bfrag[j + 4] = (short)(f1 >> 16);
        }
        const int ca = s * 4 + kq;                  // A 16B-chunk, XOR-(tok&7) swizzled
        bf16x8 a0 = *(const bf16x8*)(bA + (ln      ) * 128 + ((ca) ^ (ln & 7)) * 16);
        bf16x8 a1 = *(const bf16x8*)(bA + (ln + 16) * 128 + ((ca) ^ (ln & 7)) * 16);
        bf16x8 a2 = *(const bf16x8*)(bA + (ln + 32) * 128 + ((ca) ^ (ln & 7)) * 16);
        bf16x8 a3 = *(const bf16x8*)(bA + (ln + 48) * 128 + ((ca) ^ (ln & 7)) * 16);
        acc[0] = __builtin_amdgcn_mfma_f32_16x16x32_bf16(a0, bfrag, acc[0], 0, 0, 0);
        acc[1] = __builtin_amdgcn_mfma_f32_16x16x32_bf16(a1, bfrag, acc[1], 0, 0, 0);
        acc[2] = __builtin_amdgcn_mfma_f32_16x16x32_bf16(a2, bfrag, acc[2], 0, 0, 0);
        acc[3] = __builtin_amdgcn_mfma_f32_16x16x32_bf16(a3, bfrag, acc[3], 0, 0, 0);
    }
}

__global__ __launch_bounds__(BLOCK) void w8a16_main(
    const int* __restrict__ w, const unsigned short* __restrict__ xbf,
    float* __restrict__ pws) {

    __shared__ alignas(16) char ldsB[2][NCH * KT * 4];   // 2 x 16 KB
    __shared__ alignas(16) char ldsA[2][TOKENS * KT * 2];// 2 x  8 KB

    const int tid  = threadIdx.x;
    const int wv   = tid >> 6;          // 0..3: channel group within block
    const int lane = tid & 63;
    const int ln   = lane & 15;
    const int kq   = lane >> 4;

    const int kh   = blockIdx.x & 1;    // K-half
    const int n0   = (blockIdx.x >> 1) * NCH;
    const int koff = kh * KHALF;        // element offset (ints for B, halves for A)

    const int wi = detect_wint(w, lane);

    auto stage = [&](int t, int db) {
        // B tile: 64 rows x 16 chunks of 16 B (XOR row&15 swizzle, self-inverse)
        #pragma unroll
        for (int j = 0; j < 4; ++j) {
            const int idx = j * 256 + tid;
            const int r   = idx >> 4;
            const int cg  = (idx & 15) ^ (r & 15);
            const int* g  = w + (size_t)(n0 + r) * IN_F + koff + t * KT + cg * 4;
            __builtin_amdgcn_global_load_lds(
                (const __attribute__((address_space(1))) unsigned int*)g,
                (__attribute__((address_space(3))) unsigned int*)(&ldsB[db][idx * 16]),
                16, 0, 0);
        }
        // A tile: 64 tokens x 8 chunks of 16 B (XOR tok&7 swizzle)
        #pragma unroll
        for (int j = 0; j < 2; ++j) {
            const int idx = j * 256 + tid;
            const int tok = idx >> 3;
            const int cg  = (idx & 7) ^ (tok & 7);
            const unsigned short* g = xbf + (size_t)tok * IN_F + koff + t * KT + cg * 8;
            __builtin_amdgcn_global_load_lds(
                (const __attribute__((address_space(1))) unsigned int*)g,
                (__attribute__((address_space(3))) unsigned int*)(&ldsA[db][idx * 16]),
                16, 0, 0);
        }
    };

    f32x4 acc[4] = {};

    stage(0, 0);
    __syncthreads();
    for (int t = 0; t < NTILES; ++t) {
        if (t + 1 < NTILES) stage(t + 1, (t + 1) & 1);
        if (wi) tile_compute<1>(ldsB[t & 1], ldsA[t & 1], wv, ln, kq, acc);
        else    tile_compute<0>(ldsB[t & 1], ldsA[t & 1], wv, ln, kq, acc);
        __syncthreads();
    }

    // f32 partials: pws[kh][m][n]  (D layout m89: col=ln, row m = 16*i + kq*4 + r)
    float* pp = pws + (size_t)kh * TOKENS * OUT_F;
    const int n = n0 + wv * 16 + ln;
    #pragma unroll
    for (int i = 0; i < 4; ++i)
        #pragma unroll
        for (int r = 0; r < 4; ++r)
            pp[(size_t)(16 * i + kq * 4 + r) * OUT_F + n] = acc[i][r];
}

// ---------------- reduce: K-half combine + scale/bias + format I/O -----------
__global__ __launch_bounds__(256) void reduce_k(
    const float* __restrict__ pws, const void* __restrict__ xv,
    const void* __restrict__ sv, const void* __restrict__ bv,
    void* __restrict__ yv) {

    const int t    = blockIdx.x * 256 + threadIdx.x;  // 262144 threads x 4 outputs
    const int lane = threadIdx.x & 63;
    const int xf = detect_fmt16(xv, lane, 9.7e-4f, 64.0f);
    const int sf = detect_fmt16(sv, lane, 1.0e-4f, 0.25f);

    const int base = t * 4;
    const int m    = base >> 14;          // token
    const int n    = base & 16383;        // channel (4 consecutive)

    f32x4 p0 = *(const f32x4*)(pws + (size_t)m * OUT_F + n);
    f32x4 p1 = *(const f32x4*)(pws + (size_t)TOKENS * OUT_F + (size_t)m * OUT_F + n);

    float sc[4], bi[4];
    if (sf == F_FP32) {
        f32x4 s4 = *(const f32x4*)((const float*)sv + n);
        f32x4 b4 = *(const f32x4*)((const float*)bv + n);
        #pragma unroll
        for (int j = 0; j < 4; ++j) { sc[j] = s4[j]; bi[j] = b4[j]; }
    } else if (sf == F_BF16) {
        u16x4 s4 = *(const u16x4*)((const unsigned short*)sv + n);
        u16x4 b4 = *(const u16x4*)((const unsigned short*)bv + n);
        #pragma unroll
        for (int j = 0; j < 4; ++j) { sc[j] = dec_bf16(s4[j]); bi[j] = dec_bf16(b4[j]); }
    } else {
        u16x4 s4 = *(const u16x4*)((const unsigned short*)sv + n);
        u16x4 b4 = *(const u16x4*)((const unsigned short*)bv + n);
        #pragma unroll
        for (int j = 0; j < 4; ++j) { sc[j] = dec_fp16(s4[j]); bi[j] = dec_fp16(b4[j]); }
    }

    f32x4 v;
    #pragma unroll
    for (int j = 0; j < 4; ++j) v[j] = (p0[j] + p1[j]) * sc[j] + bi[j];

    if (xf == F_FP32) {
        *(f32x4*)((float*)yv + base) = v;
    } else if (xf == F_BF16) {
        u16x4 o;
        #pragma unroll
        for (int j = 0; j < 4; ++j) o[j] = enc_bf16_rne(v[j]);
        *(u16x4*)((unsigned short*)yv + base) = o;
    } else {
        u16x4 o;
        #pragma unroll
        for (int j = 0; j < 4; ++j) {
            __half h = __float2half(v[j]);
            o[j] = *(unsigned short*)&h;
        }
        *(u16x4*)((unsigned short*)yv + base) = o;
    }
}

extern "C" void kernel_launch(void* const* d_in, const int* in_sizes, int n_in,
                              void* d_out, int out_size, void* d_ws, size_t ws_size,
                              hipStream_t stream) {
    unsigned short* xbf = (unsigned short*)d_ws;                   // 512 KB
    float*          pws = (float*)((char*)d_ws + 524288);          // 8 MB partials

    prep_x<<<64, 256, 0, stream>>>(d_in[0], xbf);
    w8a16_main<<<(OUT_F / NCH) * 2, BLOCK, 0, stream>>>((const int*)d_in[1], xbf, pws);
    reduce_k<<<1024, 256, 0, stream>>>(pws, d_in[0], d_in[2], d_in[3], d_out);
}